// Round 3
// baseline (171.501 us; speedup 1.0000x reference)
//
#include <hip/hip_runtime.h>
#include <math.h>

// N=4, C=256, H=W=32, NH=2, HD=128, MAX_DIS=7, WS=15, WW=225, T=sqrt(128)
// out: [hw=1024][n=4][c=256] fp32

typedef __attribute__((ext_vector_type(8))) short short8;
typedef __attribute__((ext_vector_type(4))) short short4v;
typedef __attribute__((ext_vector_type(4))) float floatx4;

__device__ __forceinline__ short f2bf(float f) {
    unsigned u = __float_as_uint(f);
    unsigned r = (u + 0x7fffu + ((u >> 16) & 1u)) >> 16;
    return (short)r;
}
__device__ __forceinline__ float bf2f(short s) {
    return __uint_as_float(((unsigned)(unsigned short)s) << 16);
}

// ---------------------------------------------------------------------------
// conv_w: weights only -> bf16 hi/lo A-fragments.
// z 0..3: Wq,Wk,Wv,Wfc ; z 4..5: Wrel per head (15 w-tiles, zero-padded).
// 64-thread blocks, grid (16, 8, 6).
// ---------------------------------------------------------------------------
__global__ __launch_bounds__(64)
void conv_w(const float* __restrict__ Wq, const float* __restrict__ Wk,
            const float* __restrict__ Wv, const float* __restrict__ Wfc,
            const float* __restrict__ Wrel,
            short* __restrict__ Whi, short* __restrict__ Wlo,
            short* __restrict__ Wrh, short* __restrict__ Wrl)
{
    const int lane = threadIdx.x;
    const int n16 = lane & 15, quad = lane >> 4;
    const int z = blockIdx.z;

    if (z < 4) {
        const float* W = (z == 0 ? Wq : z == 1 ? Wk : z == 2 ? Wv : Wfc);
        const int dt = blockIdx.x, kc = blockIdx.y;
        const int d = dt * 16 + n16, cb = kc * 32 + quad * 8;
        float4 w0 = *(const float4*)&W[d * 256 + cb];
        float4 w1 = *(const float4*)&W[d * 256 + cb + 4];
        float f[8] = {w0.x, w0.y, w0.z, w0.w, w1.x, w1.y, w1.z, w1.w};
        short8 h8, l8;
#pragma unroll
        for (int j = 0; j < 8; ++j) {
            short hb = f2bf(f[j]);
            h8[j] = hb;
            l8[j] = f2bf(f[j] - bf2f(hb));
        }
        long off = (long)z * 65536 + (((long)(dt * 8 + kc) * 64) + lane) * 8;
        *(short8*)(Whi + off) = h8;
        *(short8*)(Wlo + off) = l8;
    } else {
        const int g = z - 4;
        const int wt = blockIdx.x, kc = blockIdx.y;
        if (wt >= 15 || kc >= 4) return;
        const int w = wt * 16 + n16;         // 0..239, valid < 225
        const int cb = kc * 32 + quad * 8;
        float f[8] = {0.f, 0.f, 0.f, 0.f, 0.f, 0.f, 0.f, 0.f};
        if (w < 225) {
            float4 w0 = *(const float4*)&Wrel[(long)(g * 225 + w) * 128 + cb];
            float4 w1 = *(const float4*)&Wrel[(long)(g * 225 + w) * 128 + cb + 4];
            f[0] = w0.x; f[1] = w0.y; f[2] = w0.z; f[3] = w0.w;
            f[4] = w1.x; f[5] = w1.y; f[6] = w1.z; f[7] = w1.w;
        }
        short8 h8, l8;
#pragma unroll
        for (int j = 0; j < 8; ++j) {
            short hb = f2bf(f[j]);
            h8[j] = hb;
            l8[j] = f2bf(f[j] - bf2f(hb));
        }
        long off = (long)g * 30720 + (((long)(wt * 4 + kc) * 64) + lane) * 8;
        *(short8*)(Wrh + off) = h8;
        *(short8*)(Wrl + off) = l8;
    }
}

// ---------------------------------------------------------------------------
// mfma_proj v3: raw-input staging fused in (X frag intermediate eliminated).
// grid (mt16 64, z 12) = 768 blocks. Block stages X[16 m][256 c] via LDS once,
// builds B-frags in registers per kc, computes ALL 16 d-tiles (4 per wave).
// Epilogues: sel 0/1 -> x-major bf16 hi/lo (q unscaled, k * 1/T);
//            sel 2   -> padded vpad + zero this block's (row, side) pad.
// Arithmetic identical to v2 (same staged floats, same f2bf, same kc order).
// ---------------------------------------------------------------------------
__global__ __launch_bounds__(256)
void mfma_proj(const float* __restrict__ q, const float* __restrict__ k,
               const float* __restrict__ v,
               const short* __restrict__ Whi, const short* __restrict__ Wlo,
               const float* __restrict__ bq, const float* __restrict__ bk,
               const float* __restrict__ bv,
               short* __restrict__ qhi, short* __restrict__ qlo,
               short* __restrict__ khi, short* __restrict__ klo,
               float* __restrict__ vpad)
{
    __shared__ float st[256 * 17];       // staging [c 256][m 16 +1]; aliased as tile[16][257]
    const int tid = threadIdx.x;
    const int wave = tid >> 6, lane = tid & 63;
    const int n16 = lane & 15, quad = lane >> 4;
    const int mt16 = blockIdx.x, z = blockIdx.y;
    const int sel = z >> 2, batch = z & 3;

    const float* X = (sel == 0 ? q : sel == 1 ? k : v) + ((long)batch << 18);

    // ---- stage X tile: thread tid = channel c, 16 m's ----
    {
        const float* src = X + ((long)tid << 10) + mt16 * 16;
        float4 a0 = *(const float4*)(src);
        float4 a1 = *(const float4*)(src + 4);
        float4 a2 = *(const float4*)(src + 8);
        float4 a3 = *(const float4*)(src + 12);
        float* d = &st[tid * 17];
        d[0] = a0.x; d[1] = a0.y; d[2] = a0.z; d[3] = a0.w;
        d[4] = a1.x; d[5] = a1.y; d[6] = a1.z; d[7] = a1.w;
        d[8] = a2.x; d[9] = a2.y; d[10] = a2.z; d[11] = a2.w;
        d[12] = a3.x; d[13] = a3.y; d[14] = a3.z; d[15] = a3.w;
    }

    const float* bias = (sel == 0 ? bq : sel == 1 ? bk : bv);
    float bbv[4][4];
#pragma unroll
    for (int i = 0; i < 4; ++i) {
        float4 b4 = *(const float4*)&bias[(wave * 4 + i) * 16 + quad * 4];
        bbv[i][0] = b4.x; bbv[i][1] = b4.y; bbv[i][2] = b4.z; bbv[i][3] = b4.w;
    }
    __syncthreads();

    floatx4 acc[4] = {{0.f,0.f,0.f,0.f},{0.f,0.f,0.f,0.f},
                      {0.f,0.f,0.f,0.f},{0.f,0.f,0.f,0.f}};
    const long abase = (long)sel * 65536 + (long)lane * 8;
#pragma unroll
    for (int kc = 0; kc < 8; ++kc) {
        // B-frag from staged LDS (same elements conv produced before)
        short8 bh, bl;
        const float* col = &st[(kc * 32 + quad * 8) * 17 + n16];
#pragma unroll
        for (int j = 0; j < 8; ++j) {
            float f = col[j * 17];
            short hb = f2bf(f);
            bh[j] = hb;
            bl[j] = f2bf(f - bf2f(hb));
        }
#pragma unroll
        for (int i = 0; i < 4; ++i) {
            const int dt = wave * 4 + i;
            short8 ahi = *(const short8*)(Whi + abase + (long)(dt * 8 + kc) * 512);
            short8 alo = *(const short8*)(Wlo + abase + (long)(dt * 8 + kc) * 512);
            acc[i] = __builtin_amdgcn_mfma_f32_16x16x32_bf16(ahi, bh, acc[i], 0, 0, 0);
            acc[i] = __builtin_amdgcn_mfma_f32_16x16x32_bf16(ahi, bl, acc[i], 0, 0, 0);
            acc[i] = __builtin_amdgcn_mfma_f32_16x16x32_bf16(alo, bh, acc[i], 0, 0, 0);
        }
    }

    if (sel == 2) {
        float* Y = vpad + (long)batch * 393216;
        const int m = mt16 * 16 + n16;
        const int row = m >> 5, col = (m & 31) + 8;
#pragma unroll
        for (int i = 0; i < 4; ++i) {
            const int dt = wave * 4 + i;
#pragma unroll
            for (int r = 0; r < 4; ++r)
                Y[(long)(dt * 16 + quad * 4 + r) * 1536 + row * 48 + col] = acc[i][r] + bbv[i][r];
        }
        // zero pad columns: this block handles (row = mt16>>1, side = mt16&1), all 256 ch
        {
            const int prow = mt16 >> 1, side = mt16 & 1;
            long po = (long)tid * 1536 + prow * 48 + side * 40;
            float4 zz = {0.f, 0.f, 0.f, 0.f};
            *(float4*)&Y[po] = zz;
            *(float4*)&Y[po + 4] = zz;
        }
        return;
    }

    // sel 0/1: stage D[16 m][256 c] (alias st) then x-major bf16 hi/lo
    __syncthreads();                      // st B-frag reads done
    float* tile = st;
#pragma unroll
    for (int i = 0; i < 4; ++i) {
        const int dt = wave * 4 + i;
#pragma unroll
        for (int r = 0; r < 4; ++r)
            tile[n16 * 257 + dt * 16 + quad * 4 + r] = acc[i][r] + bbv[i][r];
    }
    __syncthreads();

    const float scale = (sel == 1) ? 0.08838834764831845f : 1.0f;
    const int m_l = tid >> 4, c16 = (tid & 15) * 16;
    const int m = mt16 * 16 + m_l;
    short* oh = sel ? khi : qhi;
    short* ol = sel ? klo : qlo;
#pragma unroll
    for (int half = 0; half < 2; ++half) {
        const int cg = c16 + half * 8;
        short8 h8, l8;
#pragma unroll
        for (int j = 0; j < 8; ++j) {
            float f = tile[m_l * 257 + cg + j] * scale;
            short hb = f2bf(f);
            h8[j] = hb;
            l8[j] = f2bf(f - bf2f(hb));
        }
        const int g = cg >> 7, ch = cg & 127;
        const long base = (((long)(batch * 2 + g) << 10) + m) * 128 + ch;
        *(short8*)(oh + base) = h8;
        *(short8*)(ol + base) = l8;
    }
}

// ---------------------------------------------------------------------------
// scores_pv (unchanged from round 2): scores + softmax + PV + V_bias fused.
// grid: 1024 linear blocks, XCD swizzle bz = lin&7, chh channel split.
// ---------------------------------------------------------------------------
__global__ __launch_bounds__(256)
void scores_pv(const short* __restrict__ qhi, const short* __restrict__ qlo,
               const short* __restrict__ khi, const short* __restrict__ klo,
               const short* __restrict__ Wrh, const short* __restrict__ Wrl,
               const float* __restrict__ brel,
               const float* __restrict__ vpad, const float* __restrict__ Vbias,
               short* __restrict__ AGhi, short* __restrict__ AGlo)
{
    __shared__ __align__(16) float smem[16 * 241 + 225 * 16];
    __shared__ float invl[16];
    float* qk   = smem;              // [16][241], dead after phase T
    float* pa2  = smem + 16 * 241;   // [225][16]
    float* tile = smem;              // [16][68], aliases qk in phase F

    const int tid = threadIdx.x;
    const int wave = tid >> 6, lane = tid & 63;
    const int lin = blockIdx.x;
    const int bz  = lin & 7;         // XCD-resident head/batch
    const int r2  = lin >> 3;
    const int chh = r2 & 1;          // PV channel half
    const int yy  = r2 >> 1;
    const int y   = yy >> 1;
    const int xt  = yy & 1;
    const int g = bz & 1;
    const int x0 = xt * 16;

    const int n16 = lane & 15, quad = lane >> 4;
    const long qbase = (((long)bz << 10) + y * 32 + x0 + n16) * 128 + quad * 8;
    short8 a_hi[4], a_lo[4];
#pragma unroll
    for (int ch = 0; ch < 4; ++ch) {
        a_hi[ch] = *(const short8*)(qhi + qbase + ch * 32);
        a_lo[ch] = *(const short8*)(qlo + qbase + ch * 32);
    }

    // ---- phase R: rel logits ----
    for (int wt = wave; wt < 15; wt += 4) {
        const short* Ah = Wrh + (long)g * 30720 + ((long)(wt * 4) * 64 + lane) * 8;
        const short* Al = Wrl + (long)g * 30720 + ((long)(wt * 4) * 64 + lane) * 8;
        floatx4 racc = {0.f, 0.f, 0.f, 0.f};
#pragma unroll
        for (int kc = 0; kc < 4; ++kc) {
            short8 whh = *(const short8*)(Ah + kc * 512);
            short8 wll = *(const short8*)(Al + kc * 512);
            racc = __builtin_amdgcn_mfma_f32_16x16x32_bf16(whh, a_hi[kc], racc, 0, 0, 0);
            racc = __builtin_amdgcn_mfma_f32_16x16x32_bf16(whh, a_lo[kc], racc, 0, 0, 0);
            racc = __builtin_amdgcn_mfma_f32_16x16x32_bf16(wll, a_hi[kc], racc, 0, 0, 0);
        }
#pragma unroll
        for (int r = 0; r < 4; ++r) {
            int w = wt * 16 + quad * 4 + r;
            if (w < 225) {
                int dy = w / 15, dx = w - dy * 15;
                qk[n16 * 241 + dy * 16 + dx] = racc[r] + brel[g * 225 + w];
            }
        }
    }
    __syncthreads();

    // ---- phase M: mask invalid neighbors and pad slots ----
    for (int e = tid; e < 16 * 241; e += 256) {
        int px = e / 241, idx = e - px * 241;
        int dy = idx >> 4, dx = idx & 15;
        int hy = y + dy - 7, hx = x0 + px + dx - 7;
        bool valid = (dx < 15) && (dy < 15) &&
                     (hy >= 0) && (hy < 32) && (hx >= 0) && (hx < 32);
        if (!valid) qk[e] = -1e8f;
    }
    __syncthreads();

    // ---- phase B: band QK^T ----
    for (int dy = wave; dy < 15; dy += 4) {
        const int ky = y + dy - 7;
        if (ky < 0 || ky > 31) continue;
#pragma unroll
        for (int kxt = 0; kxt < 2; ++kxt) {
            const int kxg = x0 - 8 + kxt * 16 + n16;
            const long kb = (((long)bz << 10) + ky * 32 + kxg) * 128 + quad * 8;
            floatx4 acc = {0.f, 0.f, 0.f, 0.f};
#pragma unroll
            for (int ch = 0; ch < 4; ++ch) {
                short8 b_hi = *(const short8*)(khi + kb + ch * 32);
                short8 b_lo = *(const short8*)(klo + kb + ch * 32);
                acc = __builtin_amdgcn_mfma_f32_16x16x32_bf16(a_hi[ch], b_hi, acc, 0, 0, 0);
                acc = __builtin_amdgcn_mfma_f32_16x16x32_bf16(a_hi[ch], b_lo, acc, 0, 0, 0);
                acc = __builtin_amdgcn_mfma_f32_16x16x32_bf16(a_lo[ch], b_hi, acc, 0, 0, 0);
            }
            if (kxg >= 0 && kxg < 32) {
#pragma unroll
                for (int r = 0; r < 4; ++r) {
                    int m = quad * 4 + r;
                    int dx = kxg - (x0 + m) + 7;
                    if (dx >= 0 && dx < 15) {
                        int s = m * 241 + dy * 16 + dx;
                        qk[s] = qk[s] + acc[r];
                    }
                }
            }
        }
    }
    __syncthreads();

    // ---- softmax ----
    {
        int px = tid >> 4, s = tid & 15;
        float mx = -3.0e38f;
        for (int w = s; w < 240; w += 16) mx = fmaxf(mx, qk[px * 241 + w]);
#pragma unroll
        for (int msk = 8; msk; msk >>= 1) mx = fmaxf(mx, __shfl_xor(mx, msk));
        float sum = 0.f;
        for (int w = s; w < 240; w += 16) {
            float p = __expf(qk[px * 241 + w] - mx);
            qk[px * 241 + w] = p;
            sum += p;
        }
#pragma unroll
        for (int msk = 8; msk; msk >>= 1) sum += __shfl_xor(sum, msk);
        if (s == 0) invl[px] = 1.0f / sum;
    }
    __syncthreads();

    // ---- phase T: normalize + transpose to w-major ----
    for (int e = tid; e < 3600; e += 256) {
        int w = e >> 4, px = e & 15;
        int dy2 = w / 15, dx2 = w - dy2 * 15;
        pa2[w * 16 + px] = qk[px * 241 + dy2 * 16 + dx2] * invl[px];
    }
    __syncthreads();
    // qk region is dead from here on (PV reads pa2 only); tile aliases it.

    // ---- phase P: scalar PV + V_bias, this block's 64-channel half ----
    const int n = bz >> 1;
    const int chg = tid >> 2;            // 0..63 -> 1 channel each
    const int xq  = tid & 3;             // 0..3  -> 4 px each
    const int c0  = chh * 64 + chg;      // channel within head
    const int xb  = x0 + xq * 4;         // vpad col base
    const float* v0 = vpad + (long)bz * 196608 + (long)c0 * 1536;
    const float* b0 = Vbias + (g * 128 + c0) * 225;

    float acc0[4] = {0.f, 0.f, 0.f, 0.f};

    for (int dy = 0; dy < 15; ++dy) {
        int hy = y + dy - 7;
        if (hy < 0 || hy > 31) continue;           // p == 0 for this dy
        const float4* r0 = (const float4*)(v0 + hy * 48 + xb);
        float wa[20];
#pragma unroll
        for (int t = 0; t < 5; ++t) {
            float4 a = r0[t];
            wa[4*t+0] = a.x; wa[4*t+1] = a.y; wa[4*t+2] = a.z; wa[4*t+3] = a.w;
        }
        const float* par = &pa2[dy * 15 * 16 + xq * 4];
        const float* vb0 = b0 + dy * 15;
#pragma unroll
        for (int dx = 0; dx < 15; ++dx) {
            float4 p4 = *(const float4*)&par[dx * 16];
            float ba = vb0[dx];
            acc0[0] += p4.x * (wa[1 + dx] + ba);
            acc0[1] += p4.y * (wa[2 + dx] + ba);
            acc0[2] += p4.z * (wa[3 + dx] + ba);
            acc0[3] += p4.w * (wa[4 + dx] + ba);
        }
    }

    // ---- phase F: stage [16 px][64 ch] then AG frag conversion ----
#pragma unroll
    for (int i = 0; i < 4; ++i)
        tile[(xq * 4 + i) * 68 + chg] = acc0[i];
    __syncthreads();

    const int sub = tid >> 6;            // kcp 0..3; only 0,1 used
    if (sub < 2) {
        short8 h8, l8;
#pragma unroll
        for (int j = 0; j < 8; ++j) {
            float f = tile[n16 * 68 + sub * 32 + quad * 8 + j];
            short hb = f2bf(f);
            h8[j] = hb;
            l8[j] = f2bf(f - bf2f(hb));
        }
        const int mt16 = y * 2 + xt;
        const int kc = g * 4 + chh * 2 + sub;
        long off = (long)n * 262144 + (((long)(mt16 * 8 + kc) * 64) + lane) * 8;
        *(short8*)(AGhi + off) = h8;
        *(short8*)(AGlo + off) = l8;
    }
}

// ---------------------------------------------------------------------------
// mfma_fc v3: grid (mt16 64, db2 2, nz 4) = 512 blocks.
// Each wave computes 2 d-tiles sharing one B-frag load (AG re-reads halved).
// ---------------------------------------------------------------------------
__global__ __launch_bounds__(256)
void mfma_fc(const short* __restrict__ Ahi, const short* __restrict__ Alo,
             const short* __restrict__ Whi, const short* __restrict__ Wlo,
             const float* __restrict__ bfc, float* __restrict__ out)
{
    __shared__ float tile[16 * 132];
    const int tid = threadIdx.x;
    const int wave = tid >> 6, lane = tid & 63;
    const int n16 = lane & 15, quad = lane >> 4;
    const int mt16 = blockIdx.x, db2 = blockIdx.y, nz = blockIdx.z;
    const int dt0 = db2 * 8 + wave * 2;

    const short* Bh = Ahi + (long)nz * 262144;
    const short* Bl = Alo + (long)nz * 262144;
    const long abase = (long)3 * 65536 + (long)lane * 8;

    float bbv[2][4];
#pragma unroll
    for (int p = 0; p < 2; ++p) {
        float4 b4 = *(const float4*)&bfc[(dt0 + p) * 16 + quad * 4];
        bbv[p][0] = b4.x; bbv[p][1] = b4.y; bbv[p][2] = b4.z; bbv[p][3] = b4.w;
    }

    floatx4 acc[2] = {{0.f,0.f,0.f,0.f},{0.f,0.f,0.f,0.f}};
#pragma unroll
    for (int kc = 0; kc < 8; ++kc) {
        const long bo = (long)(mt16 * 8 + kc) * 512 + (long)lane * 8;
        short8 bh = *(const short8*)(Bh + bo);
        short8 bl = *(const short8*)(Bl + bo);
#pragma unroll
        for (int p = 0; p < 2; ++p) {
            const int dt = dt0 + p;
            short8 ahi = *(const short8*)(Whi + abase + (long)(dt * 8 + kc) * 512);
            short8 alo = *(const short8*)(Wlo + abase + (long)(dt * 8 + kc) * 512);
            acc[p] = __builtin_amdgcn_mfma_f32_16x16x32_bf16(ahi, bh, acc[p], 0, 0, 0);
            acc[p] = __builtin_amdgcn_mfma_f32_16x16x32_bf16(ahi, bl, acc[p], 0, 0, 0);
            acc[p] = __builtin_amdgcn_mfma_f32_16x16x32_bf16(alo, bh, acc[p], 0, 0, 0);
        }
    }

#pragma unroll
    for (int p = 0; p < 2; ++p) {
        const int dl = (wave * 2 + p) * 16 + quad * 4;
#pragma unroll
        for (int r = 0; r < 4; ++r)
            tile[n16 * 132 + dl + r] = acc[p][r] + bbv[p][r];
    }
    __syncthreads();

    const int m_l = tid >> 4, d8 = (tid & 15) * 8;
    float4 o0 = *(const float4*)&tile[m_l * 132 + d8];
    float4 o1 = *(const float4*)&tile[m_l * 132 + d8 + 4];
    long ob = (long)(mt16 * 16 + m_l) * 1024 + nz * 256 + db2 * 128 + d8;
    *(float4*)&out[ob] = o0;
    *(float4*)&out[ob + 4] = o1;
}

// ---------------------------------------------------------------------------
// ws floats: vpad@2097152(1572864)
//   qhi@6561792 qlo@7086080 khi@7610368 klo@8134656 (as shorts, 524288 fl ea)
//   Whi@11804672(131072) Wlo@11935744
//   AGhi@12066816(524288) AGlo@12591104 Wrh@13115392(30720) Wrl@13146112
// (Xhi/Xlo regions now unused — staging fused into mfma_proj)
// ---------------------------------------------------------------------------
extern "C" void kernel_launch(void* const* d_in, const int* in_sizes, int n_in,
                              void* d_out, int out_size, void* d_ws, size_t ws_size,
                              hipStream_t stream)
{
    const float* q    = (const float*)d_in[0];
    const float* k    = (const float*)d_in[1];
    const float* v    = (const float*)d_in[2];
    const float* Wq   = (const float*)d_in[3];
    const float* bq   = (const float*)d_in[4];
    const float* Wk   = (const float*)d_in[5];
    const float* bk   = (const float*)d_in[6];
    const float* Wv   = (const float*)d_in[7];
    const float* bv   = (const float*)d_in[8];
    const float* Wrel = (const float*)d_in[9];
    const float* brel = (const float*)d_in[10];
    const float* Vb   = (const float*)d_in[11];
    const float* Wfc  = (const float*)d_in[12];
    const float* bfc  = (const float*)d_in[13];
    float* out = (float*)d_out;

    float* ws   = (float*)d_ws;
    float* vpad = ws + 2097152;
    short* qhi  = (short*)(ws + 6561792);
    short* qlo  = (short*)(ws + 7086080);
    short* khi  = (short*)(ws + 7610368);
    short* klo  = (short*)(ws + 8134656);
    short* Whi  = (short*)(ws + 11804672);
    short* Wlo  = (short*)(ws + 11935744);
    short* AGhi = (short*)(ws + 12066816);
    short* AGlo = (short*)(ws + 12591104);
    short* Wrh  = (short*)(ws + 13115392);
    short* Wrl  = (short*)(ws + 13146112);

    // weight fragment conversion only: 768 small blocks, 64 threads
    conv_w<<<dim3(16, 8, 6), dim3(64), 0, stream>>>(Wq, Wk, Wv, Wfc, Wrel,
                                                    Whi, Wlo, Wrh, Wrl);

    // QKV projections, raw-input staging fused: 768 blocks
    mfma_proj<<<dim3(64, 12), dim3(256), 0, stream>>>(q, k, v, Whi, Wlo,
                                                      bq, bk, bv,
                                                      qhi, qlo, khi, klo, vpad);

    // rel + scores + softmax + PV + V_bias -> AG frags: 1024 blocks
    scores_pv<<<dim3(1024), dim3(256), 0, stream>>>(qhi, qlo, khi, klo,
                                                    Wrh, Wrl, brel,
                                                    vpad, Vb, AGhi, AGlo);

    // FC via MFMA: 512 blocks, B-frag shared across 2 d-tiles/wave
    mfma_fc<<<dim3(64, 2, 4), dim3(256), 0, stream>>>(AGhi, AGlo, Whi, Wlo,
                                                      bfc, out);
}

// Round 4
// 162.420 us; speedup vs baseline: 1.0559x; 1.0559x over previous
//
#include <hip/hip_runtime.h>
#include <math.h>

// N=4, C=256, H=W=32, NH=2, HD=128, MAX_DIS=7, WS=15, WW=225, T=sqrt(128)
// out: [hw=1024][n=4][c=256] fp32

typedef __attribute__((ext_vector_type(8))) short short8;
typedef __attribute__((ext_vector_type(4))) short short4v;
typedef __attribute__((ext_vector_type(4))) float floatx4;

__device__ __forceinline__ short f2bf(float f) {
    unsigned u = __float_as_uint(f);
    unsigned r = (u + 0x7fffu + ((u >> 16) & 1u)) >> 16;
    return (short)r;
}
__device__ __forceinline__ float bf2f(short s) {
    return __uint_as_float(((unsigned)(unsigned short)s) << 16);
}

// ---------------------------------------------------------------------------
// conv_w: constants -> bf16 hi/lo fragments.
// z 0..3: Wq,Wk,Wv,Wfc A-frags; z 4..5: Wrel per head (15 w-tiles, padded);
// z 6..7: V_bias per head -> B-frag rows [g][128ch][256w] (w>=225 zero).
// 64-thread blocks, grid (16, 8, 8).
// ---------------------------------------------------------------------------
__global__ __launch_bounds__(64)
void conv_w(const float* __restrict__ Wq, const float* __restrict__ Wk,
            const float* __restrict__ Wv, const float* __restrict__ Wfc,
            const float* __restrict__ Wrel, const float* __restrict__ Vb,
            short* __restrict__ Whi, short* __restrict__ Wlo,
            short* __restrict__ Wrh, short* __restrict__ Wrl,
            short* __restrict__ Vbh, short* __restrict__ Vbl)
{
    const int lane = threadIdx.x;
    const int n16 = lane & 15, quad = lane >> 4;
    const int z = blockIdx.z;

    if (z < 4) {
        const float* W = (z == 0 ? Wq : z == 1 ? Wk : z == 2 ? Wv : Wfc);
        const int dt = blockIdx.x, kc = blockIdx.y;
        const int d = dt * 16 + n16, cb = kc * 32 + quad * 8;
        float4 w0 = *(const float4*)&W[d * 256 + cb];
        float4 w1 = *(const float4*)&W[d * 256 + cb + 4];
        float f[8] = {w0.x, w0.y, w0.z, w0.w, w1.x, w1.y, w1.z, w1.w};
        short8 h8, l8;
#pragma unroll
        for (int j = 0; j < 8; ++j) {
            short hb = f2bf(f[j]);
            h8[j] = hb;
            l8[j] = f2bf(f[j] - bf2f(hb));
        }
        long off = (long)z * 65536 + (((long)(dt * 8 + kc) * 64) + lane) * 8;
        *(short8*)(Whi + off) = h8;
        *(short8*)(Wlo + off) = l8;
    } else if (z < 6) {
        const int g = z - 4;
        const int wt = blockIdx.x, kc = blockIdx.y;
        if (wt >= 15 || kc >= 4) return;
        const int w = wt * 16 + n16;         // 0..239, valid < 225
        const int cb = kc * 32 + quad * 8;
        float f[8] = {0.f, 0.f, 0.f, 0.f, 0.f, 0.f, 0.f, 0.f};
        if (w < 225) {
            float4 w0 = *(const float4*)&Wrel[(long)(g * 225 + w) * 128 + cb];
            float4 w1 = *(const float4*)&Wrel[(long)(g * 225 + w) * 128 + cb + 4];
            f[0] = w0.x; f[1] = w0.y; f[2] = w0.z; f[3] = w0.w;
            f[4] = w1.x; f[5] = w1.y; f[6] = w1.z; f[7] = w1.w;
        }
        short8 h8, l8;
#pragma unroll
        for (int j = 0; j < 8; ++j) {
            short hb = f2bf(f[j]);
            h8[j] = hb;
            l8[j] = f2bf(f[j] - bf2f(hb));
        }
        long off = (long)g * 30720 + (((long)(wt * 4 + kc) * 64) + lane) * 8;
        *(short8*)(Wrh + off) = h8;
        *(short8*)(Wrl + off) = l8;
    } else {
        // V_bias: [g][128][225] -> bf16 hi/lo rows padded to 256
        const int g = z - 6;
        const int dt = blockIdx.x, wk = blockIdx.y;
        if (dt >= 8) return;
        const int ch = dt * 16 + n16;
        const int w0 = wk * 32 + quad * 8;
        float f[8];
#pragma unroll
        for (int j = 0; j < 8; ++j) {
            int w = w0 + j;
            f[j] = (w < 225) ? Vb[(long)(g * 128 + ch) * 225 + w] : 0.f;
        }
        short8 h8, l8;
#pragma unroll
        for (int j = 0; j < 8; ++j) {
            short hb = f2bf(f[j]);
            h8[j] = hb;
            l8[j] = f2bf(f[j] - bf2f(hb));
        }
        long off = (((long)(g * 128 + ch)) << 8) + w0;
        *(short8*)(Vbh + off) = h8;
        *(short8*)(Vbl + off) = l8;
    }
}

// ---------------------------------------------------------------------------
// mfma_proj v4: raw-input staging fused; V epilogue now writes TRANSPOSED
// bf16 hi/lo padded V: vhi/vlo [bz 8][ch 128][y 32][x 48] (x-pad 8 each side).
// grid (mt16 64, z 12) = 768 blocks.
// ---------------------------------------------------------------------------
__global__ __launch_bounds__(256)
void mfma_proj(const float* __restrict__ q, const float* __restrict__ k,
               const float* __restrict__ v,
               const short* __restrict__ Whi, const short* __restrict__ Wlo,
               const float* __restrict__ bq, const float* __restrict__ bk,
               const float* __restrict__ bv,
               short* __restrict__ qhi, short* __restrict__ qlo,
               short* __restrict__ khi, short* __restrict__ klo,
               short* __restrict__ vhi, short* __restrict__ vlo)
{
    __shared__ float st[256 * 17];       // staging [c 256][m 16 +1]; aliased as tile[16][257]
    const int tid = threadIdx.x;
    const int wave = tid >> 6, lane = tid & 63;
    const int n16 = lane & 15, quad = lane >> 4;
    const int mt16 = blockIdx.x, z = blockIdx.y;
    const int sel = z >> 2, batch = z & 3;

    const float* X = (sel == 0 ? q : sel == 1 ? k : v) + ((long)batch << 18);

    // ---- stage X tile: thread tid = channel c, 16 m's ----
    {
        const float* src = X + ((long)tid << 10) + mt16 * 16;
        float4 a0 = *(const float4*)(src);
        float4 a1 = *(const float4*)(src + 4);
        float4 a2 = *(const float4*)(src + 8);
        float4 a3 = *(const float4*)(src + 12);
        float* d = &st[tid * 17];
        d[0] = a0.x; d[1] = a0.y; d[2] = a0.z; d[3] = a0.w;
        d[4] = a1.x; d[5] = a1.y; d[6] = a1.z; d[7] = a1.w;
        d[8] = a2.x; d[9] = a2.y; d[10] = a2.z; d[11] = a2.w;
        d[12] = a3.x; d[13] = a3.y; d[14] = a3.z; d[15] = a3.w;
    }

    const float* bias = (sel == 0 ? bq : sel == 1 ? bk : bv);
    float bbv[4][4];
#pragma unroll
    for (int i = 0; i < 4; ++i) {
        float4 b4 = *(const float4*)&bias[(wave * 4 + i) * 16 + quad * 4];
        bbv[i][0] = b4.x; bbv[i][1] = b4.y; bbv[i][2] = b4.z; bbv[i][3] = b4.w;
    }
    __syncthreads();

    floatx4 acc[4] = {{0.f,0.f,0.f,0.f},{0.f,0.f,0.f,0.f},
                      {0.f,0.f,0.f,0.f},{0.f,0.f,0.f,0.f}};
    const long abase = (long)sel * 65536 + (long)lane * 8;
#pragma unroll
    for (int kc = 0; kc < 8; ++kc) {
        short8 bh, bl;
        const float* col = &st[(kc * 32 + quad * 8) * 17 + n16];
#pragma unroll
        for (int j = 0; j < 8; ++j) {
            float f = col[j * 17];
            short hb = f2bf(f);
            bh[j] = hb;
            bl[j] = f2bf(f - bf2f(hb));
        }
#pragma unroll
        for (int i = 0; i < 4; ++i) {
            const int dt = wave * 4 + i;
            short8 ahi = *(const short8*)(Whi + abase + (long)(dt * 8 + kc) * 512);
            short8 alo = *(const short8*)(Wlo + abase + (long)(dt * 8 + kc) * 512);
            acc[i] = __builtin_amdgcn_mfma_f32_16x16x32_bf16(ahi, bh, acc[i], 0, 0, 0);
            acc[i] = __builtin_amdgcn_mfma_f32_16x16x32_bf16(ahi, bl, acc[i], 0, 0, 0);
            acc[i] = __builtin_amdgcn_mfma_f32_16x16x32_bf16(alo, bh, acc[i], 0, 0, 0);
        }
    }

    if (sel == 2) {
        const int m = mt16 * 16 + n16;
        const int yq = m >> 5, col = (m & 31) + 8;
#pragma unroll
        for (int i = 0; i < 4; ++i) {
            const int dt = wave * 4 + i;
#pragma unroll
            for (int r = 0; r < 4; ++r) {
                const int ch = dt * 16 + quad * 4 + r;      // 0..255
                const int gg = ch >> 7, chh = ch & 127;
                float f = acc[i][r] + bbv[i][r];
                short hb = f2bf(f);
                short lb = f2bf(f - bf2f(hb));
                long o = (((long)((batch * 2 + gg) * 128 + chh) * 32 + yq)) * 48 + col;
                vhi[o] = hb;
                vlo[o] = lb;
            }
        }
        // zero x-pads: this block zeroes (row = mt16>>1, side = mt16&1), all 256 ch
        {
            const int prow = mt16 >> 1, side = mt16 & 1;
            const int gg = tid >> 7, chp = tid & 127;
            long po = (((long)((batch * 2 + gg) * 128 + chp) * 32 + prow)) * 48 + side * 40;
            short8 zz = {0,0,0,0,0,0,0,0};
            *(short8*)(vhi + po) = zz;
            *(short8*)(vlo + po) = zz;
        }
        return;
    }

    // sel 0/1: stage D[16 m][256 c] (alias st) then x-major bf16 hi/lo
    __syncthreads();                      // st B-frag reads done
    float* tile = st;
#pragma unroll
    for (int i = 0; i < 4; ++i) {
        const int dt = wave * 4 + i;
#pragma unroll
        for (int r = 0; r < 4; ++r)
            tile[n16 * 257 + dt * 16 + quad * 4 + r] = acc[i][r] + bbv[i][r];
    }
    __syncthreads();

    const float scale = (sel == 1) ? 0.08838834764831845f : 1.0f;
    const int m_l = tid >> 4, c16 = (tid & 15) * 16;
    const int m = mt16 * 16 + m_l;
    short* oh = sel ? khi : qhi;
    short* ol = sel ? klo : qlo;
#pragma unroll
    for (int half = 0; half < 2; ++half) {
        const int cg = c16 + half * 8;
        short8 h8, l8;
#pragma unroll
        for (int j = 0; j < 8; ++j) {
            float f = tile[m_l * 257 + cg + j] * scale;
            short hb = f2bf(f);
            h8[j] = hb;
            l8[j] = f2bf(f - bf2f(hb));
        }
        const int g = cg >> 7, ch = cg & 127;
        const long base = (((long)(batch * 2 + g) << 10) + m) * 128 + ch;
        *(short8*)(oh + base) = h8;
        *(short8*)(ol + base) = l8;
    }
}

// ---------------------------------------------------------------------------
// scores_pv (round-15): scores + softmax + MFMA-PV + MFMA-bias fused.
// grid 512 linear blocks, XCD swizzle bz = lin&7. Block = 16px x 128ch.
// Phase R: rel logits; M: mask; B: band QK^T; softmax;
// T: normalize + bf16 hi/lo P into pah/pal [16][264];
// A: bias GEMM  P[16x225] x Vbh[225x128] (8 k-chunks, MFMA);
// V: banded GEMM per dy: P'band[16x32] x Vrows[32x128] (MFMA, vhi/vlo);
// F: stage tile + AG frag writeback (4 kc per block).
// No divergent scalar loads remain.
// ---------------------------------------------------------------------------
__global__ __launch_bounds__(256)
void scores_pv(const short* __restrict__ qhi, const short* __restrict__ qlo,
               const short* __restrict__ khi, const short* __restrict__ klo,
               const short* __restrict__ Wrh, const short* __restrict__ Wrl,
               const float* __restrict__ brel,
               const short* __restrict__ vhi, const short* __restrict__ vlo,
               const short* __restrict__ Vbh, const short* __restrict__ Vbl,
               short* __restrict__ AGhi, short* __restrict__ AGlo)
{
    __shared__ __align__(16) float qk[16 * 241];   // 15.4 KB; aliased as tile[16][133] in F
    __shared__ __align__(16) short pah[16 * 264];  // 8.25 KB  P hi (rows padded to 264)
    __shared__ __align__(16) short pal[16 * 264];  // 8.25 KB  P lo
    __shared__ float invl[16];

    const int tid = threadIdx.x;
    const int wave = tid >> 6, lane = tid & 63;
    const int lin = blockIdx.x;
    const int bz  = lin & 7;         // XCD-resident head/batch
    const int yy  = lin >> 3;        // 0..63
    const int y   = yy >> 1;
    const int xt  = yy & 1;
    const int g = bz & 1;
    const int x0 = xt * 16;

    const int n16 = lane & 15, quad = lane >> 4;
    const long qbase = (((long)bz << 10) + y * 32 + x0 + n16) * 128 + quad * 8;
    short8 a_hi[4], a_lo[4];
#pragma unroll
    for (int ch = 0; ch < 4; ++ch) {
        a_hi[ch] = *(const short8*)(qhi + qbase + ch * 32);
        a_lo[ch] = *(const short8*)(qlo + qbase + ch * 32);
    }

    // ---- phase R: rel logits ----
    for (int wt = wave; wt < 15; wt += 4) {
        const short* Ah = Wrh + (long)g * 30720 + ((long)(wt * 4) * 64 + lane) * 8;
        const short* Al = Wrl + (long)g * 30720 + ((long)(wt * 4) * 64 + lane) * 8;
        floatx4 racc = {0.f, 0.f, 0.f, 0.f};
#pragma unroll
        for (int kc = 0; kc < 4; ++kc) {
            short8 whh = *(const short8*)(Ah + kc * 512);
            short8 wll = *(const short8*)(Al + kc * 512);
            racc = __builtin_amdgcn_mfma_f32_16x16x32_bf16(whh, a_hi[kc], racc, 0, 0, 0);
            racc = __builtin_amdgcn_mfma_f32_16x16x32_bf16(whh, a_lo[kc], racc, 0, 0, 0);
            racc = __builtin_amdgcn_mfma_f32_16x16x32_bf16(wll, a_hi[kc], racc, 0, 0, 0);
        }
#pragma unroll
        for (int r = 0; r < 4; ++r) {
            int w = wt * 16 + quad * 4 + r;
            if (w < 225) {
                int dy = w / 15, dx = w - dy * 15;
                qk[n16 * 241 + dy * 16 + dx] = racc[r] + brel[g * 225 + w];
            }
        }
    }
    __syncthreads();

    // ---- phase M: mask invalid neighbors and pad slots ----
    for (int e = tid; e < 16 * 241; e += 256) {
        int px = e / 241, idx = e - px * 241;
        int dy = idx >> 4, dx = idx & 15;
        int hy = y + dy - 7, hx = x0 + px + dx - 7;
        bool valid = (dx < 15) && (dy < 15) &&
                     (hy >= 0) && (hy < 32) && (hx >= 0) && (hx < 32);
        if (!valid) qk[e] = -1e8f;
    }
    __syncthreads();

    // ---- phase B: band QK^T ----
    for (int dy = wave; dy < 15; dy += 4) {
        const int ky = y + dy - 7;
        if (ky < 0 || ky > 31) continue;
#pragma unroll
        for (int kxt = 0; kxt < 2; ++kxt) {
            const int kxg = x0 - 8 + kxt * 16 + n16;
            const long kb = (((long)bz << 10) + ky * 32 + kxg) * 128 + quad * 8;
            floatx4 acc = {0.f, 0.f, 0.f, 0.f};
#pragma unroll
            for (int ch = 0; ch < 4; ++ch) {
                short8 b_hi = *(const short8*)(khi + kb + ch * 32);
                short8 b_lo = *(const short8*)(klo + kb + ch * 32);
                acc = __builtin_amdgcn_mfma_f32_16x16x32_bf16(a_hi[ch], b_hi, acc, 0, 0, 0);
                acc = __builtin_amdgcn_mfma_f32_16x16x32_bf16(a_hi[ch], b_lo, acc, 0, 0, 0);
                acc = __builtin_amdgcn_mfma_f32_16x16x32_bf16(a_lo[ch], b_hi, acc, 0, 0, 0);
            }
            if (kxg >= 0 && kxg < 32) {
#pragma unroll
                for (int r = 0; r < 4; ++r) {
                    int m = quad * 4 + r;
                    int dx = kxg - (x0 + m) + 7;
                    if (dx >= 0 && dx < 15) {
                        int s = m * 241 + dy * 16 + dx;
                        qk[s] = qk[s] + acc[r];
                    }
                }
            }
        }
    }
    __syncthreads();

    // ---- softmax ----
    {
        int px = tid >> 4, s = tid & 15;
        float mx = -3.0e38f;
        for (int w = s; w < 240; w += 16) mx = fmaxf(mx, qk[px * 241 + w]);
#pragma unroll
        for (int msk = 8; msk; msk >>= 1) mx = fmaxf(mx, __shfl_xor(mx, msk));
        float sum = 0.f;
        for (int w = s; w < 240; w += 16) {
            float p = __expf(qk[px * 241 + w] - mx);
            qk[px * 241 + w] = p;
            sum += p;
        }
#pragma unroll
        for (int msk = 8; msk; msk >>= 1) sum += __shfl_xor(sum, msk);
        if (s == 0) invl[px] = 1.0f / sum;
    }
    __syncthreads();

    // ---- phase T: normalize + bf16 hi/lo into pah/pal (w >= 225 -> 0) ----
    for (int e = tid; e < 4096; e += 256) {
        int px = e >> 8, w = e & 255;
        float p = 0.f;
        if (w < 225) {
            int dy2 = w / 15, dx2 = w - dy2 * 15;
            p = qk[px * 241 + dy2 * 16 + dx2] * invl[px];
        }
        short hb = f2bf(p);
        pah[px * 264 + w] = hb;
        pal[px * 264 + w] = f2bf(p - bf2f(hb));
    }
    __syncthreads();
    // qk is dead from here on; tile aliases it in phase F.

    // ---- phases A+V: MFMA accumulation, 2 ch-tiles per wave ----
    floatx4 acc[2] = {{0.f,0.f,0.f,0.f},{0.f,0.f,0.f,0.f}};
    const int ch0a = (wave * 2) * 16;        // tile 0 channel base
    const int ch0b = (wave * 2 + 1) * 16;    // tile 1

    // (A) bias GEMM: P[16 x 225] x Vbh[225 x 128], 8 k-chunks of 32
#pragma unroll
    for (int wk = 0; wk < 8; ++wk) {
        short8 pa_h = *(const short8*)&pah[n16 * 264 + wk * 32 + quad * 8];
        short8 pa_l = *(const short8*)&pal[n16 * 264 + wk * 32 + quad * 8];
        const long vb0 = (((long)(g * 128 + ch0a + n16)) << 8) + wk * 32 + quad * 8;
        const long vb1 = (((long)(g * 128 + ch0b + n16)) << 8) + wk * 32 + quad * 8;
        short8 b0h = *(const short8*)(Vbh + vb0);
        short8 b0l = *(const short8*)(Vbl + vb0);
        short8 b1h = *(const short8*)(Vbh + vb1);
        short8 b1l = *(const short8*)(Vbl + vb1);
        acc[0] = __builtin_amdgcn_mfma_f32_16x16x32_bf16(pa_h, b0h, acc[0], 0, 0, 0);
        acc[0] = __builtin_amdgcn_mfma_f32_16x16x32_bf16(pa_h, b0l, acc[0], 0, 0, 0);
        acc[0] = __builtin_amdgcn_mfma_f32_16x16x32_bf16(pa_l, b0h, acc[0], 0, 0, 0);
        acc[1] = __builtin_amdgcn_mfma_f32_16x16x32_bf16(pa_h, b1h, acc[1], 0, 0, 0);
        acc[1] = __builtin_amdgcn_mfma_f32_16x16x32_bf16(pa_h, b1l, acc[1], 0, 0, 0);
        acc[1] = __builtin_amdgcn_mfma_f32_16x16x32_bf16(pa_l, b1h, acc[1], 0, 0, 0);
    }

    // (V) banded GEMM per dy: P'[px][k] = P[px][dy*15 + k-px-1], k-cols = x0-8..x0+23
    for (int dy = 0; dy < 15; ++dy) {
        const int ky = y + dy - 7;
        if (ky < 0 || ky > 31) continue;    // those P rows are exactly 0
        short8 bnd_h, bnd_l;
        const int rowoff = n16 * 264 + dy * 15 - n16 - 1;
#pragma unroll
        for (int j = 0; j < 8; ++j) {
            int kk = quad * 8 + j;
            int dx = kk - n16 - 1;
            bool valid = (unsigned)dx < 15u;
            int idx = valid ? (rowoff + kk) : 0;
            short vh = pah[idx];
            short vl = pal[idx];
            bnd_h[j] = valid ? vh : (short)0;
            bnd_l[j] = valid ? vl : (short)0;
        }
        const long v0o = (((long)((bz * 128 + ch0a + n16)) * 32 + ky)) * 48 + x0 + quad * 8;
        const long v1o = (((long)((bz * 128 + ch0b + n16)) * 32 + ky)) * 48 + x0 + quad * 8;
        short8 v0h = *(const short8*)(vhi + v0o);
        short8 v0l = *(const short8*)(vlo + v0o);
        short8 v1h = *(const short8*)(vhi + v1o);
        short8 v1l = *(const short8*)(vlo + v1o);
        acc[0] = __builtin_amdgcn_mfma_f32_16x16x32_bf16(bnd_h, v0h, acc[0], 0, 0, 0);
        acc[0] = __builtin_amdgcn_mfma_f32_16x16x32_bf16(bnd_h, v0l, acc[0], 0, 0, 0);
        acc[0] = __builtin_amdgcn_mfma_f32_16x16x32_bf16(bnd_l, v0h, acc[0], 0, 0, 0);
        acc[1] = __builtin_amdgcn_mfma_f32_16x16x32_bf16(bnd_h, v1h, acc[1], 0, 0, 0);
        acc[1] = __builtin_amdgcn_mfma_f32_16x16x32_bf16(bnd_h, v1l, acc[1], 0, 0, 0);
        acc[1] = __builtin_amdgcn_mfma_f32_16x16x32_bf16(bnd_l, v1h, acc[1], 0, 0, 0);
    }

    // ---- phase F: stage tile [16 px][128 ch] then AG frag conversion ----
    float* tile = qk;                    // [16][133]
#pragma unroll
    for (int t = 0; t < 2; ++t) {
        const int cb = (wave * 2 + t) * 16 + n16;
#pragma unroll
        for (int r = 0; r < 4; ++r)
            tile[(quad * 4 + r) * 133 + cb] = acc[t][r];
    }
    __syncthreads();

    const int sub = tid >> 6;            // kcp 0..3
    short8 h8, l8;
#pragma unroll
    for (int j = 0; j < 8; ++j) {
        float f = tile[n16 * 133 + sub * 32 + quad * 8 + j];
        short hb = f2bf(f);
        h8[j] = hb;
        l8[j] = f2bf(f - bf2f(hb));
    }
    const int n = bz >> 1;
    const int mt16 = y * 2 + xt;
    const int kc = g * 4 + sub;
    long off = (long)n * 262144 + (((long)(mt16 * 8 + kc) * 64) + lane) * 8;
    *(short8*)(AGhi + off) = h8;
    *(short8*)(AGlo + off) = l8;
}

// ---------------------------------------------------------------------------
// mfma_fc v3: grid (mt16 64, db2 2, nz 4) = 512 blocks.
// ---------------------------------------------------------------------------
__global__ __launch_bounds__(256)
void mfma_fc(const short* __restrict__ Ahi, const short* __restrict__ Alo,
             const short* __restrict__ Whi, const short* __restrict__ Wlo,
             const float* __restrict__ bfc, float* __restrict__ out)
{
    __shared__ float tile[16 * 132];
    const int tid = threadIdx.x;
    const int wave = tid >> 6, lane = tid & 63;
    const int n16 = lane & 15, quad = lane >> 4;
    const int mt16 = blockIdx.x, db2 = blockIdx.y, nz = blockIdx.z;
    const int dt0 = db2 * 8 + wave * 2;

    const short* Bh = Ahi + (long)nz * 262144;
    const short* Bl = Alo + (long)nz * 262144;
    const long abase = (long)3 * 65536 + (long)lane * 8;

    float bbv[2][4];
#pragma unroll
    for (int p = 0; p < 2; ++p) {
        float4 b4 = *(const float4*)&bfc[(dt0 + p) * 16 + quad * 4];
        bbv[p][0] = b4.x; bbv[p][1] = b4.y; bbv[p][2] = b4.z; bbv[p][3] = b4.w;
    }

    floatx4 acc[2] = {{0.f,0.f,0.f,0.f},{0.f,0.f,0.f,0.f}};
#pragma unroll
    for (int kc = 0; kc < 8; ++kc) {
        const long bo = (long)(mt16 * 8 + kc) * 512 + (long)lane * 8;
        short8 bh = *(const short8*)(Bh + bo);
        short8 bl = *(const short8*)(Bl + bo);
#pragma unroll
        for (int p = 0; p < 2; ++p) {
            const int dt = dt0 + p;
            short8 ahi = *(const short8*)(Whi + abase + (long)(dt * 8 + kc) * 512);
            short8 alo = *(const short8*)(Wlo + abase + (long)(dt * 8 + kc) * 512);
            acc[p] = __builtin_amdgcn_mfma_f32_16x16x32_bf16(ahi, bh, acc[p], 0, 0, 0);
            acc[p] = __builtin_amdgcn_mfma_f32_16x16x32_bf16(ahi, bl, acc[p], 0, 0, 0);
            acc[p] = __builtin_amdgcn_mfma_f32_16x16x32_bf16(alo, bh, acc[p], 0, 0, 0);
        }
    }

#pragma unroll
    for (int p = 0; p < 2; ++p) {
        const int dl = (wave * 2 + p) * 16 + quad * 4;
#pragma unroll
        for (int r = 0; r < 4; ++r)
            tile[n16 * 132 + dl + r] = acc[p][r] + bbv[p][r];
    }
    __syncthreads();

    const int m_l = tid >> 4, d8 = (tid & 15) * 8;
    float4 o0 = *(const float4*)&tile[m_l * 132 + d8];
    float4 o1 = *(const float4*)&tile[m_l * 132 + d8 + 4];
    long ob = (long)(mt16 * 16 + m_l) * 1024 + nz * 256 + db2 * 128 + d8;
    *(float4*)&out[ob] = o0;
    *(float4*)&out[ob + 4] = o1;
}

// ---------------------------------------------------------------------------
// ws floats:
//   vhi@2097152 (786432 fl as shorts) vlo@2883584
//   Vbh@4718592 (32768 fl) Vbl@4751360
//   qhi@6561792 qlo@7086080 khi@7610368 klo@8134656 (524288 fl each)
//   Whi@11804672(131072) Wlo@11935744
//   AGhi@12066816(524288) AGlo@12591104 Wrh@13115392(30720) Wrl@13146112
// ---------------------------------------------------------------------------
extern "C" void kernel_launch(void* const* d_in, const int* in_sizes, int n_in,
                              void* d_out, int out_size, void* d_ws, size_t ws_size,
                              hipStream_t stream)
{
    const float* q    = (const float*)d_in[0];
    const float* k    = (const float*)d_in[1];
    const float* v    = (const float*)d_in[2];
    const float* Wq   = (const float*)d_in[3];
    const float* bq   = (const float*)d_in[4];
    const float* Wk   = (const float*)d_in[5];
    const float* bk   = (const float*)d_in[6];
    const float* Wv   = (const float*)d_in[7];
    const float* bv   = (const float*)d_in[8];
    const float* Wrel = (const float*)d_in[9];
    const float* brel = (const float*)d_in[10];
    const float* Vb   = (const float*)d_in[11];
    const float* Wfc  = (const float*)d_in[12];
    const float* bfc  = (const float*)d_in[13];
    float* out = (float*)d_out;

    float* ws   = (float*)d_ws;
    short* vhi  = (short*)(ws + 2097152);
    short* vlo  = (short*)(ws + 2883584);
    short* Vbh  = (short*)(ws + 4718592);
    short* Vbl  = (short*)(ws + 4751360);
    short* qhi  = (short*)(ws + 6561792);
    short* qlo  = (short*)(ws + 7086080);
    short* khi  = (short*)(ws + 7610368);
    short* klo  = (short*)(ws + 8134656);
    short* Whi  = (short*)(ws + 11804672);
    short* Wlo  = (short*)(ws + 11935744);
    short* AGhi = (short*)(ws + 12066816);
    short* AGlo = (short*)(ws + 12591104);
    short* Wrh  = (short*)(ws + 13115392);
    short* Wrl  = (short*)(ws + 13146112);

    // constant fragment conversion: weights, Wrel, V_bias
    conv_w<<<dim3(16, 8, 8), dim3(64), 0, stream>>>(Wq, Wk, Wv, Wfc, Wrel, Vb,
                                                    Whi, Wlo, Wrh, Wrl, Vbh, Vbl);

    // QKV projections, raw-input staging fused; V -> transposed bf16 hi/lo
    mfma_proj<<<dim3(64, 12), dim3(256), 0, stream>>>(q, k, v, Whi, Wlo,
                                                      bq, bk, bv,
                                                      qhi, qlo, khi, klo,
                                                      vhi, vlo);

    // rel + scores + softmax + MFMA PV + MFMA bias -> AG frags: 512 blocks
    scores_pv<<<dim3(512), dim3(256), 0, stream>>>(qhi, qlo, khi, klo,
                                                   Wrh, Wrl, brel,
                                                   vhi, vlo, Vbh, Vbl,
                                                   AGhi, AGlo);

    // FC via MFMA: 512 blocks, B-frag shared across 2 d-tiles/wave
    mfma_fc<<<dim3(64, 2, 4), dim3(256), 0, stream>>>(AGhi, AGlo, Whi, Wlo,
                                                      bfc, out);
}